// Round 7
// baseline (243.619 us; speedup 1.0000x reference)
//
#include <hip/hip_runtime.h>
#include <hip/hip_bf16.h>

// ModernNCA fused bf16-MFMA pipeline, v7.
// B=512 queries, N=131072 candidates, D=192, H=256, NY=10.
// v7: k_dist dense P writes (LDS-staged, was 7.5x write-amplified),
// paired query-half dispatch for ce L3 reuse; k_encode hidden in 4
// quarters -> 35 KB LDS -> 4 blocks/CU (16 waves).
typedef __bf16 bf16;
typedef __attribute__((ext_vector_type(8))) __bf16 bf16x8;
typedef __attribute__((ext_vector_type(4))) __bf16 bf16x4;
typedef __attribute__((ext_vector_type(4))) float f32x4;

#define NQ     512
#define NC     131072
#define DIM    192
#define HID    256
#define NY     10
#define NSLICE 512           // cand slices of 256; k_dist grid = 2*NSLICE

// ---------------- workspace layout (bytes) ----------------
#define OFF_W1B 0u                              // 24 planes x 256 x 8 bf16 = 98304
#define OFF_W2B (OFF_W1B + 98304u)              // 32 planes x 192 x 8 bf16 = 98304
#define OFF_XEB (OFF_W2B + 98304u)              // 24 planes x 512 x 8 bf16 = 196608
#define OFF_X2  (OFF_XEB + 196608u)             // 512 f32 = 2048
#define OFF_CE  (OFF_X2 + 2048u)                // 131072x192 bf16 = 50331648
#define OFF_C2  (OFF_CE + 50331648u)            // 131072 f32 = 524288
#define OFF_P   (OFF_C2 + 524288u)              // 1024 blocks x 256 q x 12 f32 = 12582912

// ---------------- K0: weight cast into B-fragment plane layout ----------
// Plane p = (k>>5)*4 + ((k>>3)&3); element j = k&7.
__global__ __launch_bounds__(256) void k_prep(const float* __restrict__ W1,
                                              const float* __restrict__ W2,
                                              bf16* __restrict__ W1B,
                                              bf16* __restrict__ W2B) {
  int idx = blockIdx.x * 256 + threadIdx.x;   // 0..98303
  if (idx < 192 * 256) {
    int k = idx / 256, n = idx % 256;
    int p = (k >> 5) * 4 + ((k >> 3) & 3);
    W1B[((size_t)(p * 256 + n)) * 8 + (k & 7)] = (bf16)W1[idx];
  } else {
    int i2 = idx - 192 * 256;
    int k = i2 / 192, n = i2 % 192;
    int p = (k >> 5) * 4 + ((k >> 3) & 3);
    W2B[((size_t)(p * 192 + n)) * 8 + (k & 7)] = (bf16)W2[i2];
  }
}

// ---------------- K1/K2: encode + residual MLP (256 thr, 64 rows) --------
// Encode: wave w owns features {2w,2w+1} + cat w. Hidden processed in 4
// quarters of 64 cols (hth 9.2 KB): G1-quarter (wave w owns 16 local cols)
// -> barrier -> G2 partial accumulate. LDS 35 KB -> 4 blocks/CU, 16 waves.
__global__ __launch_bounds__(256, 4) void k_encode(
    const float* __restrict__ xn, const int* __restrict__ xc,
    const float* __restrict__ Wn, const float* __restrict__ bn,
    const float* __restrict__ emb, const float* __restrict__ b1,
    const float* __restrict__ b2, const bf16* __restrict__ W1B,
    const bf16* __restrict__ W2B, bf16* __restrict__ oe,
    bf16* __restrict__ oeB, float* __restrict__ on2) {
  __shared__ alignas(16) bf16 zt[64][200];    // encoded z / output (25.6 KB)
  __shared__ alignas(16) bf16 hth[64][72];    // hidden quarter (9.2 KB)
  __shared__ float n2l[64];

  const int t = threadIdx.x;
  const int row0 = blockIdx.x * 64;
  const int lane = t & 63, w = t >> 6;       // wave 0..3
  const int l15 = lane & 15, q = lane >> 4;

  if (t < 64) n2l[t] = 0.f;

  // ---- encode: wave w -> num features {2w,2w+1} + cat feature w ----
  {
    const int g = row0 + lane;
    float2 xv2 = *(const float2*)&xn[(size_t)g * 8 + 2 * w];
    int cv = xc[g * 4 + w];
#pragma unroll
    for (int f01 = 0; f01 < 2; f01++) {
      int f = 2 * w + f01;
      float xv = f01 ? xv2.y : xv2.x;
      f32x4 wv[4], bv[4];
#pragma unroll
      for (int i = 0; i < 4; i++) {
        wv[i] = *(const f32x4*)&Wn[f * 16 + i * 4];
        bv[i] = *(const f32x4*)&bn[f * 16 + i * 4];
      }
      bf16x8 p0, p1;
#pragma unroll
      for (int u = 0; u < 8; u++) {
        p0[u] = (bf16)(xv * wv[u >> 2][u & 3] + bv[u >> 2][u & 3]);
        p1[u] = (bf16)(xv * wv[2 + (u >> 2)][u & 3] + bv[2 + (u >> 2)][u & 3]);
      }
      *(bf16x8*)&zt[lane][f * 16] = p0;
      *(bf16x8*)&zt[lane][f * 16 + 8] = p1;
    }
    const float* er = &emb[(size_t)(w * 100 + cv) * 16];
    f32x4 e0 = *(const f32x4*)&er[0];
    f32x4 e1 = *(const f32x4*)&er[4];
    f32x4 e2 = *(const f32x4*)&er[8];
    f32x4 e3 = *(const f32x4*)&er[12];
    bf16x8 pc0, pc1;
#pragma unroll
    for (int u = 0; u < 4; u++) {
      pc0[u] = (bf16)e0[u]; pc0[4 + u] = (bf16)e1[u];
      pc1[u] = (bf16)e2[u]; pc1[4 + u] = (bf16)e3[u];
    }
    *(bf16x8*)&zt[lane][128 + w * 16] = pc0;
    *(bf16x8*)&zt[lane][128 + w * 16 + 8] = pc1;
  }
  __syncthreads();

  f32x4 z4 = {0.f, 0.f, 0.f, 0.f};
  f32x4 acc2[4][3];
#pragma unroll
  for (int mi = 0; mi < 4; mi++)
#pragma unroll
    for (int ni = 0; ni < 3; ni++) acc2[mi][ni] = z4;

#pragma unroll 1
  for (int h = 0; h < 4; ++h) {
    if (h) __syncthreads();        // prior G2 reads of hth done

    // ---- G1 quarter: wave w owns local col [w*16, w*16+16) ----
    {
      f32x4 acc1[4];
#pragma unroll
      for (int mi = 0; mi < 4; mi++) acc1[mi] = z4;
#pragma unroll 2
      for (int kk = 0; kk < 192; kk += 32) {
        bf16x8 a[4];
#pragma unroll
        for (int mi = 0; mi < 4; mi++)
          a[mi] = *(const bf16x8*)&zt[mi * 16 + l15][kk + q * 8];
        bf16x8 b = *(const bf16x8*)&W1B[(size_t)(((kk >> 5) * 4 + q) * 256 + h * 64 + w * 16 + l15) * 8];
#pragma unroll
        for (int mi = 0; mi < 4; mi++)
          acc1[mi] = __builtin_amdgcn_mfma_f32_16x16x32_bf16(a[mi], b, acc1[mi], 0, 0, 0);
      }
      int nl = w * 16 + l15;
      float bb = b1[h * 64 + nl];
#pragma unroll
      for (int mi = 0; mi < 4; mi++)
#pragma unroll
        for (int r = 0; r < 4; r++) {
          float hv = acc1[mi][r] + bb;
          hth[mi * 16 + q * 4 + r][nl] = (bf16)(hv > 0.f ? hv : 0.f);
        }
    }
    __syncthreads();

    // ---- G2 partial: k in [h*64, h*64+64); wave w owns n [48w,48w+48) ----
#pragma unroll
    for (int kk2 = 0; kk2 < 64; kk2 += 32) {
      bf16x8 a[4], b[3];
#pragma unroll
      for (int mi = 0; mi < 4; mi++)
        a[mi] = *(const bf16x8*)&hth[mi * 16 + l15][kk2 + q * 8];
      const bf16* wp = &W2B[(size_t)(((h * 2 + (kk2 >> 5)) * 4 + q) * 192 + w * 48 + l15) * 8];
#pragma unroll
      for (int ni = 0; ni < 3; ni++)
        b[ni] = *(const bf16x8*)&wp[ni * 128];
#pragma unroll
      for (int mi = 0; mi < 4; mi++)
#pragma unroll
        for (int ni = 0; ni < 3; ni++)
          acc2[mi][ni] = __builtin_amdgcn_mfma_f32_16x16x32_bf16(a[mi], b[ni], acc2[mi][ni], 0, 0, 0);
    }
  }

  // ---- epilogue: v = z + acc2 + b2, in-place in zt (wave-private cols) ----
  // No barrier needed: last in-loop barrier ordered all zt A-reads; each
  // wave touches only its own col slice [48w,48w+48).
  {
    float nrm[4][4];
#pragma unroll
    for (int mi = 0; mi < 4; mi++)
#pragma unroll
      for (int r = 0; r < 4; r++) nrm[mi][r] = 0.f;
#pragma unroll
    for (int ni = 0; ni < 3; ni++) {
      int n = w * 48 + ni * 16 + l15;
      float bb = b2[n];
#pragma unroll
      for (int mi = 0; mi < 4; mi++)
#pragma unroll
        for (int r = 0; r < 4; r++) {
          int rr = mi * 16 + q * 4 + r;
          float v = (float)zt[rr][n] + acc2[mi][ni][r] + bb;
          zt[rr][n] = (bf16)v;
          nrm[mi][r] += v * v;
        }
    }
#pragma unroll
    for (int mi = 0; mi < 4; mi++)
#pragma unroll
      for (int r = 0; r < 4; r++) {
        float s = nrm[mi][r];
        s += __shfl_xor(s, 1);
        s += __shfl_xor(s, 2);
        s += __shfl_xor(s, 4);
        s += __shfl_xor(s, 8);
        if (l15 == 0) atomicAdd(&n2l[mi * 16 + q * 4 + r], s);
      }
  }
  __syncthreads();

  // ---- copy-out ----
  if (oeB) {
    // queries: B-plane layout oeB[(p*512 + row)*8 + j], p = col/8
    for (int cc = w; cc < 24; cc += 4) {
      bf16x8 v = *(const bf16x8*)&zt[lane][cc * 8];
      *(bf16x8*)&oeB[((size_t)cc * NQ + row0 + lane) * 8] = v;
    }
  } else {
    // candidates: row-major, fully coalesced 8B granules
    uint2* dst = (uint2*)(oe + (size_t)row0 * DIM);   // 48 uint2 per row
#pragma unroll
    for (int j = t; j < 64 * 48; j += 256) {
      int r = j / 48, cc = j - r * 48;
      dst[j] = *(const uint2*)&zt[r][cc * 4];
    }
  }
  if (t < 64) on2[row0 + t] = n2l[t];
}

// ---------------- K3: dist + exp + PV, no-max flash ----------------
// Grid 1024; slice = bx>>1 (256 cands), half = bx&1 (256 queries) — the
// two halves of a slice are dispatch-adjacent for ce L2/L3 reuse.
// 256 thr (4 waves); 4 chunks of 64 cands; wave owns 32 q per qt (qt=2).
// P written DENSE: staged in LDS (reusing ct), then contiguous f32x4s.
__global__ __launch_bounds__(256, 4) void k_dist(
    const bf16* __restrict__ xeB, const float* __restrict__ x2v,
    const bf16* __restrict__ ce, const float* __restrict__ c2v,
    const float* __restrict__ cy, float* __restrict__ P) {
  __shared__ alignas(16) bf16 ct[64][200];     // chunk encodings (25.6 KB)
  __shared__ alignas(16) bf16 ET[4][16][72];   // per-wave exp tiles (9.2 KB)
  __shared__ float c2l[64];

  const int t = threadIdx.x;
  const int slice = blockIdx.x >> 1;
  const int half = blockIdx.x & 1;
  const int n0 = slice * 256;
  const int qh = half * 256;
  const int lane = t & 63, w = t >> 6;
  const int l15 = lane & 15, q = lane >> 4;

  f32x4 z4 = {0.f, 0.f, 0.f, 0.f};
  f32x4 oacc[2][2];            // [qt][nq] — accumulates across the 4 chunks
#pragma unroll
  for (int qt = 0; qt < 2; qt++)
#pragma unroll
    for (int nq = 0; nq < 2; nq++) oacc[qt][nq] = z4;

  // query norms: chunk-invariant, hoisted
  float x2a[2][2];
#pragma unroll
  for (int qt = 0; qt < 2; qt++)
#pragma unroll
    for (int nq = 0; nq < 2; nq++)
      x2a[qt][nq] = x2v[qh + qt * 128 + w * 32 + nq * 16 + l15];

#pragma unroll 1
  for (int c = 0; c < 4; ++c) {
    if (c) __syncthreads();                    // prior chunk's ct/c2l reads done
    {
      int r = t >> 2, qu = t & 3;
      const uint4* src = (const uint4*)(ce + (size_t)(n0 + c * 64 + r) * DIM);
      uint4* dst = (uint4*)&ct[r][0];
#pragma unroll
      for (int i = 0; i < 6; i++) dst[qu * 6 + i] = src[qu * 6 + i];
    }
    if (t < 16) *(f32x4*)&c2l[t * 4] = *(const f32x4*)&c2v[n0 + c * 64 + t * 4];
    __syncthreads();

    // Y B-frags for this chunk (col 10 = ones -> l)
    bf16x8 yf[2];
#pragma unroll
    for (int kb = 0; kb < 2; kb++)
#pragma unroll
      for (int jj = 0; jj < 8; jj++) {
        int cand = n0 + c * 64 + kb * 32 + q * 8 + jj;
        float v = (l15 < 10) ? cy[(size_t)cand * NY + l15]
                             : (l15 == 10 ? 1.f : 0.f);
        yf[kb][jj] = (bf16)v;
      }

#pragma unroll 1
    for (int qt = 0; qt < 2; ++qt) {
      const int qbase = qh + qt * 128 + w * 32;
      f32x4 acc[4][2];         // [mc][nq]
#pragma unroll
      for (int mc = 0; mc < 4; mc++)
#pragma unroll
        for (int nq = 0; nq < 2; nq++) acc[mc][nq] = z4;

      // dist GEMM: A = ct (LDS), B = xeB planes (global, L2-hot)
#pragma unroll 1
      for (int kk = 0; kk < 192; kk += 32) {
        bf16x8 a[4], b[2];
#pragma unroll
        for (int mc = 0; mc < 4; mc++)
          a[mc] = *(const bf16x8*)&ct[mc * 16 + l15][kk + q * 8];
        const bf16* xp = &xeB[(size_t)(((kk >> 5) * 4 + q) * NQ + qbase + l15) * 8];
#pragma unroll
        for (int nq = 0; nq < 2; nq++)
          b[nq] = *(const bf16x8*)&xp[nq * 128];
#pragma unroll
        for (int mc = 0; mc < 4; mc++)
#pragma unroll
          for (int nq = 0; nq < 2; nq++)
            acc[mc][nq] = __builtin_amdgcn_mfma_f32_16x16x32_bf16(a[mc], b[nq], acc[mc][nq], 0, 0, 0);
      }

      // per 16-query group: exp -> ET (wave-private 16 rows) -> PV MFMA
#pragma unroll
      for (int nq = 0; nq < 2; ++nq) {
#pragma unroll
        for (int mc = 0; mc < 4; mc++) {
          f32x4 cc = *(const f32x4*)&c2l[mc * 16 + q * 4];
          bf16x4 ev;
#pragma unroll
          for (int r = 0; r < 4; r++) {
            float d2 = __builtin_fmaf(-2.f, acc[mc][nq][r], x2a[qt][nq] + cc[r]);
            ev[r] = (bf16)__expf(-sqrtf(__builtin_fabsf(d2)));
          }
          *(bf16x4*)&ET[w][l15][mc * 16 + q * 4] = ev;
        }
#pragma unroll
        for (int kb = 0; kb < 2; kb++) {
          bf16x8 a = *(const bf16x8*)&ET[w][l15][kb * 32 + q * 8];
          oacc[qt][nq] = __builtin_amdgcn_mfma_f32_16x16x32_bf16(a, yf[kb], oacc[qt][nq], 0, 0, 0);
        }
      }
    }
  }

  // ---- dense P write: stage in LDS (ct is dead), then contiguous f32x4 ----
  __syncthreads();
  float* Pst = (float*)&ct[0][0];              // 256 q x 12 = 12.3 KB
  if (l15 < 11) {
#pragma unroll
    for (int qt = 0; qt < 2; qt++)
#pragma unroll
      for (int nq = 0; nq < 2; nq++)
#pragma unroll
        for (int r = 0; r < 4; r++) {
          int lq = qt * 128 + w * 32 + nq * 16 + q * 4 + r;
          Pst[lq * 12 + l15] = oacc[qt][nq][r];
        }
  }
  __syncthreads();
  {
    f32x4* Pg = (f32x4*)(P + (size_t)blockIdx.x * 3072);   // 256*12 floats
    const f32x4* Ps = (const f32x4*)Pst;
#pragma unroll
    for (int i = t; i < 768; i += 256) Pg[i] = Ps[i];
  }
}

// ---------------- K4: combine (pure sum — no max needed) ----------------
__global__ __launch_bounds__(512) void k_comb(const float* __restrict__ P,
                                              float* __restrict__ out) {
  __shared__ float red[8][11];
  const int t = threadIdx.x;
  const int qy = blockIdx.x;
  const int lane = t & 63, w = t >> 6;

  // record for (slice=t, half=qy>>8, localq=qy&255)
  const float* p = &P[((size_t)(t * 2 + (qy >> 8)) * 256 + (qy & 255)) * 12];
  f32x4 v0 = *(const f32x4*)&p[0];
  f32x4 v1 = *(const f32x4*)&p[4];
  f32x4 v2 = *(const f32x4*)&p[8];
  float s[11];
#pragma unroll
  for (int j = 0; j < 4; j++) s[j] = v0[j];
#pragma unroll
  for (int j = 0; j < 4; j++) s[4 + j] = v1[j];
#pragma unroll
  for (int j = 0; j < 3; j++) s[8 + j] = v2[j];
#pragma unroll
  for (int d = 1; d < 64; d <<= 1)
#pragma unroll
    for (int j = 0; j < 11; j++) s[j] += __shfl_xor(s[j], d);
  if (lane == 0)
#pragma unroll
    for (int j = 0; j < 11; j++) red[w][j] = s[j];
  __syncthreads();
  if (t < 10) {
    float o = 0.f, l = 0.f;
#pragma unroll
    for (int i = 0; i < 8; i++) { o += red[i][t]; l += red[i][10]; }
    out[qy * NY + t] = o / l;
  }
}

// ---------------- launcher ----------------
extern "C" void kernel_launch(void* const* d_in, const int* in_sizes, int n_in,
                              void* d_out, int out_size, void* d_ws, size_t ws_size,
                              hipStream_t stream) {
  (void)in_sizes; (void)n_in; (void)out_size; (void)ws_size;
  const float* x_num = (const float*)d_in[0];
  const int*   x_cat = (const int*)d_in[1];
  const float* c_num = (const float*)d_in[2];
  const int*   c_cat = (const int*)d_in[3];
  const float* c_y   = (const float*)d_in[4];
  const float* W_num = (const float*)d_in[5];
  const float* b_num = (const float*)d_in[6];
  const float* emb   = (const float*)d_in[7];
  const float* W1    = (const float*)d_in[8];
  const float* b1    = (const float*)d_in[9];
  const float* W2    = (const float*)d_in[10];
  const float* b2    = (const float*)d_in[11];
  float* out = (float*)d_out;

  char* ws = (char*)d_ws;
  bf16*  W1B = (bf16*)(ws + OFF_W1B);
  bf16*  W2B = (bf16*)(ws + OFF_W2B);
  bf16*  xeB = (bf16*)(ws + OFF_XEB);
  float* x2v = (float*)(ws + OFF_X2);
  bf16*  ce  = (bf16*)(ws + OFF_CE);
  float* c2v = (float*)(ws + OFF_C2);
  float* P   = (float*)(ws + OFF_P);

  k_prep<<<dim3(384), dim3(256), 0, stream>>>(W1, W2, W1B, W2B);
  k_encode<<<dim3(NQ / 64), dim3(256), 0, stream>>>(
      x_num, x_cat, W_num, b_num, emb, b1, b2, W1B, W2B, nullptr, xeB, x2v);
  k_encode<<<dim3(NC / 64), dim3(256), 0, stream>>>(
      c_num, c_cat, W_num, b_num, emb, b1, b2, W1B, W2B, ce, nullptr, c2v);
  k_dist<<<dim3(2 * NSLICE), dim3(256), 0, stream>>>(xeB, x2v, ce, c2v, c_y, P);
  k_comb<<<dim3(NQ), dim3(512), 0, stream>>>(P, out);
}

// Round 8
// 209.828 us; speedup vs baseline: 1.1610x; 1.1610x over previous
//
#include <hip/hip_runtime.h>
#include <hip/hip_bf16.h>

// ModernNCA fused bf16-MFMA pipeline, v8.
// B=512 queries, N=131072 candidates, D=192, H=256, NY=10.
// v8: k_dist qt loop FULLY UNROLLED — v5/v6/v7 indexed oacc[qt] with a
// runtime loop var under "#pragma unroll 1", which scratch-allocated the
// accumulators (~80 MB/dispatch of spill traffic = the unexplained
// WRITE_SIZE). Dispatch mapping reverted to v6 (b, b+512 share ce slice
// AND XCD). k_encode reverted to v6 two-half form.
typedef __bf16 bf16;
typedef __attribute__((ext_vector_type(8))) __bf16 bf16x8;
typedef __attribute__((ext_vector_type(4))) __bf16 bf16x4;
typedef __attribute__((ext_vector_type(4))) float f32x4;

#define NQ     512
#define NC     131072
#define DIM    192
#define HID    256
#define NY     10
#define NSLICE 512           // cand slices of 256; k_dist grid = 2*NSLICE

// ---------------- workspace layout (bytes) ----------------
#define OFF_W1B 0u                              // 24 planes x 256 x 8 bf16 = 98304
#define OFF_W2B (OFF_W1B + 98304u)              // 32 planes x 192 x 8 bf16 = 98304
#define OFF_XEB (OFF_W2B + 98304u)              // 24 planes x 512 x 8 bf16 = 196608
#define OFF_X2  (OFF_XEB + 196608u)             // 512 f32 = 2048
#define OFF_CE  (OFF_X2 + 2048u)                // 131072x192 bf16 = 50331648
#define OFF_C2  (OFF_CE + 50331648u)            // 131072 f32 = 524288
#define OFF_P   (OFF_C2 + 524288u)              // 1024 blocks x 256 q x 12 f32 = 12582912

// ---------------- K0: weight cast into B-fragment plane layout ----------
// Plane p = (k>>5)*4 + ((k>>3)&3); element j = k&7.
__global__ __launch_bounds__(256) void k_prep(const float* __restrict__ W1,
                                              const float* __restrict__ W2,
                                              bf16* __restrict__ W1B,
                                              bf16* __restrict__ W2B) {
  int idx = blockIdx.x * 256 + threadIdx.x;   // 0..98303
  if (idx < 192 * 256) {
    int k = idx / 256, n = idx % 256;
    int p = (k >> 5) * 4 + ((k >> 3) & 3);
    W1B[((size_t)(p * 256 + n)) * 8 + (k & 7)] = (bf16)W1[idx];
  } else {
    int i2 = idx - 192 * 256;
    int k = i2 / 192, n = i2 % 192;
    int p = (k >> 5) * 4 + ((k >> 3) & 3);
    W2B[((size_t)(p * 192 + n)) * 8 + (k & 7)] = (bf16)W2[i2];
  }
}

// ---------------- K1/K2: encode + residual MLP (256 thr, 64 rows) --------
// v6 form: hidden in 2 halves of 128 cols (hth 17.4 KB); LDS 43 KB ->
// 3 blocks/CU. All register indices compile-time.
__global__ __launch_bounds__(256, 3) void k_encode(
    const float* __restrict__ xn, const int* __restrict__ xc,
    const float* __restrict__ Wn, const float* __restrict__ bn,
    const float* __restrict__ emb, const float* __restrict__ b1,
    const float* __restrict__ b2, const bf16* __restrict__ W1B,
    const bf16* __restrict__ W2B, bf16* __restrict__ oe,
    bf16* __restrict__ oeB, float* __restrict__ on2) {
  __shared__ alignas(16) bf16 zt[64][200];    // encoded z / output (25.6 KB)
  __shared__ alignas(16) bf16 hth[64][136];   // hidden half (17.4 KB)
  __shared__ float n2l[64];

  const int t = threadIdx.x;
  const int row0 = blockIdx.x * 64;
  const int lane = t & 63, w = t >> 6;       // wave 0..3
  const int l15 = lane & 15, q = lane >> 4;

  if (t < 64) n2l[t] = 0.f;

  // ---- encode: wave w -> num features {2w,2w+1} + cat feature w ----
  {
    const int g = row0 + lane;
    float2 xv2 = *(const float2*)&xn[(size_t)g * 8 + 2 * w];
    int cv = xc[g * 4 + w];
#pragma unroll
    for (int f01 = 0; f01 < 2; f01++) {
      int f = 2 * w + f01;
      float xv = f01 ? xv2.y : xv2.x;
      f32x4 wv[4], bv[4];
#pragma unroll
      for (int i = 0; i < 4; i++) {
        wv[i] = *(const f32x4*)&Wn[f * 16 + i * 4];
        bv[i] = *(const f32x4*)&bn[f * 16 + i * 4];
      }
      bf16x8 p0, p1;
#pragma unroll
      for (int u = 0; u < 8; u++) {
        p0[u] = (bf16)(xv * wv[u >> 2][u & 3] + bv[u >> 2][u & 3]);
        p1[u] = (bf16)(xv * wv[2 + (u >> 2)][u & 3] + bv[2 + (u >> 2)][u & 3]);
      }
      *(bf16x8*)&zt[lane][f * 16] = p0;
      *(bf16x8*)&zt[lane][f * 16 + 8] = p1;
    }
    const float* er = &emb[(size_t)(w * 100 + cv) * 16];
    f32x4 e0 = *(const f32x4*)&er[0];
    f32x4 e1 = *(const f32x4*)&er[4];
    f32x4 e2 = *(const f32x4*)&er[8];
    f32x4 e3 = *(const f32x4*)&er[12];
    bf16x8 pc0, pc1;
#pragma unroll
    for (int u = 0; u < 4; u++) {
      pc0[u] = (bf16)e0[u]; pc0[4 + u] = (bf16)e1[u];
      pc1[u] = (bf16)e2[u]; pc1[4 + u] = (bf16)e3[u];
    }
    *(bf16x8*)&zt[lane][128 + w * 16] = pc0;
    *(bf16x8*)&zt[lane][128 + w * 16 + 8] = pc1;
  }
  __syncthreads();

  f32x4 z4 = {0.f, 0.f, 0.f, 0.f};
  f32x4 acc2[4][3];
#pragma unroll
  for (int mi = 0; mi < 4; mi++)
#pragma unroll
    for (int ni = 0; ni < 3; ni++) acc2[mi][ni] = z4;

#pragma unroll
  for (int h = 0; h < 2; ++h) {
    if (h) __syncthreads();        // prior G2 reads of hth done

    // ---- G1 half: wave w owns local cols [w*32, w*32+32) ----
    {
      f32x4 acc1[4][2];
#pragma unroll
      for (int mi = 0; mi < 4; mi++)
#pragma unroll
        for (int ni = 0; ni < 2; ni++) acc1[mi][ni] = z4;
#pragma unroll 2
      for (int kk = 0; kk < 192; kk += 32) {
        bf16x8 a[4], b[2];
#pragma unroll
        for (int mi = 0; mi < 4; mi++)
          a[mi] = *(const bf16x8*)&zt[mi * 16 + l15][kk + q * 8];
        const bf16* wp = &W1B[(size_t)(((kk >> 5) * 4 + q) * 256 + h * 128 + w * 32 + l15) * 8];
#pragma unroll
        for (int ni = 0; ni < 2; ni++)
          b[ni] = *(const bf16x8*)&wp[ni * 128];
#pragma unroll
        for (int mi = 0; mi < 4; mi++)
#pragma unroll
          for (int ni = 0; ni < 2; ni++)
            acc1[mi][ni] = __builtin_amdgcn_mfma_f32_16x16x32_bf16(a[mi], b[ni], acc1[mi][ni], 0, 0, 0);
      }
#pragma unroll
      for (int ni = 0; ni < 2; ni++) {
        int nl = w * 32 + ni * 16 + l15;
        float bb = b1[h * 128 + nl];
#pragma unroll
        for (int mi = 0; mi < 4; mi++)
#pragma unroll
          for (int r = 0; r < 4; r++) {
            float hv = acc1[mi][ni][r] + bb;
            hth[mi * 16 + q * 4 + r][nl] = (bf16)(hv > 0.f ? hv : 0.f);
          }
      }
    }
    __syncthreads();

    // ---- G2 partial: k in [h*128, h*128+128); wave w owns n [48w,48w+48) --
#pragma unroll 2
    for (int kk2 = 0; kk2 < 128; kk2 += 32) {
      bf16x8 a[4], b[3];
#pragma unroll
      for (int mi = 0; mi < 4; mi++)
        a[mi] = *(const bf16x8*)&hth[mi * 16 + l15][kk2 + q * 8];
      const bf16* wp = &W2B[(size_t)(((h * 4 + (kk2 >> 5)) * 4 + q) * 192 + w * 48 + l15) * 8];
#pragma unroll
      for (int ni = 0; ni < 3; ni++)
        b[ni] = *(const bf16x8*)&wp[ni * 128];
#pragma unroll
      for (int mi = 0; mi < 4; mi++)
#pragma unroll
        for (int ni = 0; ni < 3; ni++)
          acc2[mi][ni] = __builtin_amdgcn_mfma_f32_16x16x32_bf16(a[mi], b[ni], acc2[mi][ni], 0, 0, 0);
    }
  }

  // ---- epilogue: v = z + acc2 + b2, in-place in zt (wave-private cols) ----
  {
    float nrm[4][4];
#pragma unroll
    for (int mi = 0; mi < 4; mi++)
#pragma unroll
      for (int r = 0; r < 4; r++) nrm[mi][r] = 0.f;
#pragma unroll
    for (int ni = 0; ni < 3; ni++) {
      int n = w * 48 + ni * 16 + l15;
      float bb = b2[n];
#pragma unroll
      for (int mi = 0; mi < 4; mi++)
#pragma unroll
        for (int r = 0; r < 4; r++) {
          int rr = mi * 16 + q * 4 + r;
          float v = (float)zt[rr][n] + acc2[mi][ni][r] + bb;
          zt[rr][n] = (bf16)v;
          nrm[mi][r] += v * v;
        }
    }
#pragma unroll
    for (int mi = 0; mi < 4; mi++)
#pragma unroll
      for (int r = 0; r < 4; r++) {
        float s = nrm[mi][r];
        s += __shfl_xor(s, 1);
        s += __shfl_xor(s, 2);
        s += __shfl_xor(s, 4);
        s += __shfl_xor(s, 8);
        if (l15 == 0) atomicAdd(&n2l[mi * 16 + q * 4 + r], s);
      }
  }
  __syncthreads();

  // ---- copy-out ----
  if (oeB) {
    // queries: B-plane layout oeB[(p*512 + row)*8 + j], p = col/8
    for (int cc = w; cc < 24; cc += 4) {
      bf16x8 v = *(const bf16x8*)&zt[lane][cc * 8];
      *(bf16x8*)&oeB[((size_t)cc * NQ + row0 + lane) * 8] = v;
    }
  } else {
    // candidates: row-major, fully coalesced 8B granules
    uint2* dst = (uint2*)(oe + (size_t)row0 * DIM);   // 48 uint2 per row
#pragma unroll
    for (int j = t; j < 64 * 48; j += 256) {
      int r = j / 48, cc = j - r * 48;
      dst[j] = *(const uint2*)&zt[r][cc * 4];
    }
  }
  if (t < 64) on2[row0 + t] = n2l[t];
}

// ---------------- K3: dist + exp + PV, no-max flash ----------------
// Grid 1024 = 512 cand-slices x 2 query-halves (b and b+512 share the ce
// slice AND XCD). Block = 256 cands x 256 q; 4 chunks of 64 cands; the
// qt loop (2 iters) is FULLY UNROLLED so oacc stays in registers.
// P written dense via LDS staging.
__global__ __launch_bounds__(256, 4) void k_dist(
    const bf16* __restrict__ xeB, const float* __restrict__ x2v,
    const bf16* __restrict__ ce, const float* __restrict__ c2v,
    const float* __restrict__ cy, float* __restrict__ P) {
  __shared__ alignas(16) bf16 ct[64][200];     // chunk encodings (25.6 KB)
  __shared__ alignas(16) bf16 ET[4][16][72];   // per-wave exp tiles (9.2 KB)
  __shared__ float c2l[64];

  const int t = threadIdx.x;
  const int slice = blockIdx.x & (NSLICE - 1);
  const int half = blockIdx.x >> 9;
  const int n0 = slice * 256;
  const int qh = half * 256;
  const int lane = t & 63, w = t >> 6;
  const int l15 = lane & 15, q = lane >> 4;

  f32x4 z4 = {0.f, 0.f, 0.f, 0.f};
  f32x4 oacc[2][2];            // [qt][nq] — compile-time indexed only
#pragma unroll
  for (int qt = 0; qt < 2; qt++)
#pragma unroll
    for (int nq = 0; nq < 2; nq++) oacc[qt][nq] = z4;

#pragma unroll 1
  for (int c = 0; c < 4; ++c) {
    if (c) __syncthreads();                    // prior chunk's ct/c2l reads done
    {
      int r = t >> 2, qu = t & 3;
      const uint4* src = (const uint4*)(ce + (size_t)(n0 + c * 64 + r) * DIM);
      uint4* dst = (uint4*)&ct[r][0];
#pragma unroll
      for (int i = 0; i < 6; i++) dst[qu * 6 + i] = src[qu * 6 + i];
    }
    if (t < 16) *(f32x4*)&c2l[t * 4] = *(const f32x4*)&c2v[n0 + c * 64 + t * 4];
    __syncthreads();

    // Y B-frags for this chunk (col 10 = ones -> l)
    bf16x8 yf[2];
#pragma unroll
    for (int kb = 0; kb < 2; kb++)
#pragma unroll
      for (int jj = 0; jj < 8; jj++) {
        int cand = n0 + c * 64 + kb * 32 + q * 8 + jj;
        float v = (l15 < 10) ? cy[(size_t)cand * NY + l15]
                             : (l15 == 10 ? 1.f : 0.f);
        yf[kb][jj] = (bf16)v;
      }

#pragma unroll
    for (int qt = 0; qt < 2; ++qt) {           // FULLY UNROLLED
      const int qbase = qh + qt * 128 + w * 32;
      f32x4 acc[4][2];         // [mc][nq]
#pragma unroll
      for (int mc = 0; mc < 4; mc++)
#pragma unroll
        for (int nq = 0; nq < 2; nq++) acc[mc][nq] = z4;

      // dist GEMM: A = ct (LDS), B = xeB planes (global, L2-hot)
#pragma unroll 1
      for (int kk = 0; kk < 192; kk += 32) {
        bf16x8 a[4], b[2];
#pragma unroll
        for (int mc = 0; mc < 4; mc++)
          a[mc] = *(const bf16x8*)&ct[mc * 16 + l15][kk + q * 8];
        const bf16* xp = &xeB[(size_t)(((kk >> 5) * 4 + q) * NQ + qbase + l15) * 8];
#pragma unroll
        for (int nq = 0; nq < 2; nq++)
          b[nq] = *(const bf16x8*)&xp[nq * 128];
#pragma unroll
        for (int mc = 0; mc < 4; mc++)
#pragma unroll
          for (int nq = 0; nq < 2; nq++)
            acc[mc][nq] = __builtin_amdgcn_mfma_f32_16x16x32_bf16(a[mc], b[nq], acc[mc][nq], 0, 0, 0);
      }

      // per 16-query group: exp -> ET (wave-private 16 rows) -> PV MFMA
#pragma unroll
      for (int nq = 0; nq < 2; ++nq) {
        float x2s = x2v[qbase + nq * 16 + l15];
#pragma unroll
        for (int mc = 0; mc < 4; mc++) {
          f32x4 cc = *(const f32x4*)&c2l[mc * 16 + q * 4];
          bf16x4 ev;
#pragma unroll
          for (int r = 0; r < 4; r++) {
            float d2 = __builtin_fmaf(-2.f, acc[mc][nq][r], x2s + cc[r]);
            ev[r] = (bf16)__expf(-sqrtf(__builtin_fabsf(d2)));
          }
          *(bf16x4*)&ET[w][l15][mc * 16 + q * 4] = ev;
        }
#pragma unroll
        for (int kb = 0; kb < 2; kb++) {
          bf16x8 a = *(const bf16x8*)&ET[w][l15][kb * 32 + q * 8];
          oacc[qt][nq] = __builtin_amdgcn_mfma_f32_16x16x32_bf16(a, yf[kb], oacc[qt][nq], 0, 0, 0);
        }
      }
    }
  }

  // ---- dense P write: stage in LDS (ct is dead), then contiguous f32x4 ----
  __syncthreads();
  float* Pst = (float*)&ct[0][0];              // 256 q x 12 = 12.3 KB
  if (l15 < 11) {
#pragma unroll
    for (int qt = 0; qt < 2; qt++)
#pragma unroll
      for (int nq = 0; nq < 2; nq++)
#pragma unroll
        for (int r = 0; r < 4; r++) {
          int lq = qt * 128 + w * 32 + nq * 16 + q * 4 + r;
          Pst[lq * 12 + l15] = oacc[qt][nq][r];
        }
  }
  __syncthreads();
  {
    f32x4* Pg = (f32x4*)(P + (size_t)blockIdx.x * 3072);   // 256*12 floats
    const f32x4* Ps = (const f32x4*)Pst;
#pragma unroll
    for (int i = t; i < 768; i += 256) Pg[i] = Ps[i];
  }
}

// ---------------- K4: combine (pure sum — no max needed) ----------------
__global__ __launch_bounds__(512) void k_comb(const float* __restrict__ P,
                                              float* __restrict__ out) {
  __shared__ float red[8][11];
  const int t = threadIdx.x;
  const int qy = blockIdx.x;
  const int lane = t & 63, w = t >> 6;

  // record for (block = half*512 + slice, localq = qy&255); slice = t
  const float* p = &P[((size_t)((qy >> 8) * 512 + t) * 256 + (qy & 255)) * 12];
  f32x4 v0 = *(const f32x4*)&p[0];
  f32x4 v1 = *(const f32x4*)&p[4];
  f32x4 v2 = *(const f32x4*)&p[8];
  float s[11];
#pragma unroll
  for (int j = 0; j < 4; j++) s[j] = v0[j];
#pragma unroll
  for (int j = 0; j < 4; j++) s[4 + j] = v1[j];
#pragma unroll
  for (int j = 0; j < 3; j++) s[8 + j] = v2[j];
#pragma unroll
  for (int d = 1; d < 64; d <<= 1)
#pragma unroll
    for (int j = 0; j < 11; j++) s[j] += __shfl_xor(s[j], d);
  if (lane == 0)
#pragma unroll
    for (int j = 0; j < 11; j++) red[w][j] = s[j];
  __syncthreads();
  if (t < 10) {
    float o = 0.f, l = 0.f;
#pragma unroll
    for (int i = 0; i < 8; i++) { o += red[i][t]; l += red[i][10]; }
    out[qy * NY + t] = o / l;
  }
}

// ---------------- launcher ----------------
extern "C" void kernel_launch(void* const* d_in, const int* in_sizes, int n_in,
                              void* d_out, int out_size, void* d_ws, size_t ws_size,
                              hipStream_t stream) {
  (void)in_sizes; (void)n_in; (void)out_size; (void)ws_size;
  const float* x_num = (const float*)d_in[0];
  const int*   x_cat = (const int*)d_in[1];
  const float* c_num = (const float*)d_in[2];
  const int*   c_cat = (const int*)d_in[3];
  const float* c_y   = (const float*)d_in[4];
  const float* W_num = (const float*)d_in[5];
  const float* b_num = (const float*)d_in[6];
  const float* emb   = (const float*)d_in[7];
  const float* W1    = (const float*)d_in[8];
  const float* b1    = (const float*)d_in[9];
  const float* W2    = (const float*)d_in[10];
  const float* b2    = (const float*)d_in[11];
  float* out = (float*)d_out;

  char* ws = (char*)d_ws;
  bf16*  W1B = (bf16*)(ws + OFF_W1B);
  bf16*  W2B = (bf16*)(ws + OFF_W2B);
  bf16*  xeB = (bf16*)(ws + OFF_XEB);
  float* x2v = (float*)(ws + OFF_X2);
  bf16*  ce  = (bf16*)(ws + OFF_CE);
  float* c2v = (float*)(ws + OFF_C2);
  float* P   = (float*)(ws + OFF_P);

  k_prep<<<dim3(384), dim3(256), 0, stream>>>(W1, W2, W1B, W2B);
  k_encode<<<dim3(NQ / 64), dim3(256), 0, stream>>>(
      x_num, x_cat, W_num, b_num, emb, b1, b2, W1B, W2B, nullptr, xeB, x2v);
  k_encode<<<dim3(NC / 64), dim3(256), 0, stream>>>(
      c_num, c_cat, W_num, b_num, emb, b1, b2, W1B, W2B, ce, nullptr, c2v);
  k_dist<<<dim3(2 * NSLICE), dim3(256), 0, stream>>>(xeB, x2v, ce, c2v, c_y, P);
  k_comb<<<dim3(NQ), dim3(512), 0, stream>>>(P, out);
}